// Round 3
// baseline (2149.121 us; speedup 1.0000x reference)
//
#include <hip/hip_runtime.h>
#include <cstdint>

// Problem constants (fixed by setup_inputs: H=480, W=1024, S=32, margin=10, step=4)
#define HH 480
#define WW 1024
#define SS 32
#define HW (HH*WW)              // 491520
#define MARGIN 10
#define STEP 4
#define GYC 116                 // len(arange(10, 471, 4))
#define GXC 252                 // len(arange(10, 1015, 4))
#define GG (GYC*GXC)            // 29232 grid candidates
#define NSLOT (2*HH*WW/(STEP*STEP))  // 61440 trajectory slots
#define NBLK (NSLOT/256)        // 240 blocks -> co-resident on 256 CUs
#define NWAVE (NSLOT/64)        // 960 waves
#define CW ((GG+63)/64)         // 457 waves own candidate windows of 64

__device__ __forceinline__ int clampi(int v, int lo, int hi) {
  return v < lo ? lo : (v > hi ? hi : v);
}

// Device-scope arrive/spin barrier. Safe because all NBLK blocks are
// co-resident (240 blocks, ~0 LDS, modest VGPR, <=256 CUs). __threadfence()
// is an agent-scope acq_rel fence: drains stores to L2 and invalidates the
// CU's L1, so cross-block data is fresh after the barrier. Monotonic target.
__device__ __forceinline__ void grid_barrier(int* bar, int target) {
  __syncthreads();
  if (threadIdx.x == 0) {
    __threadfence();
    atomicAdd(bar, 1);
    while (__hip_atomic_load(bar, __ATOMIC_RELAXED, __HIP_MEMORY_SCOPE_AGENT) < target) {
      __builtin_amdgcn_s_sleep(1);
    }
    __threadfence();
  }
  __syncthreads();
}

// ---------------------------------------------------------------------------
// K0: zero the occupancy grid and the barrier counter (ws is poisoned 0xAA).
// ---------------------------------------------------------------------------
__global__ __launch_bounds__(256) void k_init(unsigned int* __restrict__ occ_words,
                                              int* __restrict__ bar)
{
  int idx = blockIdx.x * 256 + threadIdx.x;
  if (idx == 0) *bar = 0;
  if (idx < GG / 4) occ_words[idx] = 0u;
}

// ---------------------------------------------------------------------------
// K1: batched fwd-bwd consistency prune for all 31 steps (unchanged).
// ---------------------------------------------------------------------------
__global__ __launch_bounds__(256) void k_prune(const float* __restrict__ ff,
                                               const float* __restrict__ fbk,
                                               unsigned char* __restrict__ on)
{
#pragma clang fp contract(off)
  int p = blockIdx.x * 256 + threadIdx.x;
  int s = blockIdx.y;
  int y = p >> 10, x = p & 1023;              // W = 1024
  const float* f0 = ff + (size_t)s * 2 * HW;
  const float* f1 = f0 + HW;
  float fx = f0[p], fy = f1[p];
  float xt = (float)x + fx;
  float yt = (float)y + fy;
  float x0 = floorf(xt), y0 = floorf(yt);
  float wx1 = xt - x0, wx0 = 1.0f - wx1;
  float wy1 = yt - y0, wy0 = 1.0f - wy1;
  int x0i = clampi((int)x0, 0, WW - 1);
  int x1i = x0i + 1; if (x1i > WW - 1) x1i = WW - 1;
  int y0i = clampi((int)y0, 0, HH - 1);
  int y1i = y0i + 1; if (y1i > HH - 1) y1i = HH - 1;
  float w00 = wy0 * wx0, w01 = wy0 * wx1, w10 = wy1 * wx0, w11 = wy1 * wx1;
  int i00 = y0i * WW + x0i, i01 = y0i * WW + x1i;
  int i10 = y1i * WW + x0i, i11 = y1i * WW + x1i;
  const float* b0 = fbk + (size_t)s * 2 * HW;
  const float* b1 = b0 + HW;
  float bw0 = ((b0[i00] * w00 + b0[i01] * w01) + b0[i10] * w10) + b0[i11] * w11;
  float bw1 = ((b1[i00] * w00 + b1[i01] * w01) + b1[i10] * w10) + b1[i11] * w11;
  float t0 = fx + bw0, t1 = fy + bw1;
  float diff = sqrtf(t0 * t0 + t1 * t1);
  float magf = sqrtf(fx * fx + fy * fy);
  float magb = sqrtf(bw0 * bw0 + bw1 * bw1);
  float mag = 0.5f * (magf + magb);
  on[(size_t)s * HW + p] = (diff <= 0.01f * mag + 0.1f) ? (unsigned char)1 : (unsigned char)0;
}

// ---------------------------------------------------------------------------
// K2: persistent scan — all 31 steps in one launch. Thread tid owns slot tid;
// x/y/Start state lives in registers for the whole kernel. Per step:
//   A: advect + occ marking            -> barrier
//   B: ballot counts (cand free / slot free) -> barrier
//   C: prefix over 960 wave totals, write stable cand list, zero occ -> barrier
//   D: rank-matched births (owner thread applies its own birth), write row s+1
// Stable order = wave-segment asc, lane asc = index asc (matches argsort).
// ---------------------------------------------------------------------------
__global__ __launch_bounds__(256, 1) void k_steps(
    const float* __restrict__ ff, const unsigned char* __restrict__ on_all,
    float* __restrict__ X, float* __restrict__ Y, float* __restrict__ Start,
    unsigned char* __restrict__ occ, unsigned short* __restrict__ cand,
    int* __restrict__ wtot_c, int* __restrict__ wtot_s, int* bar)
{
#pragma clang fp contract(off)
  const int tid = blockIdx.x * 256 + threadIdx.x;   // slot id
  const int w = tid >> 6;                            // global wave id
  const int lane = tid & 63;
  const unsigned long long ltmask = (1ull << lane) - 1ull;

  float x = 0.f, y = 0.f, st = -1.f;
  if (tid < GG) {
    int ii = tid / GXC, jj = tid - ii * GXC;
    x = (float)(MARGIN + STEP * jj);
    y = (float)(MARGIN + STEP * ii);
    st = 0.f;
  }
  X[tid] = x; Y[tid] = y;   // row 0

  int btarget = 0;

  for (int s = 0; s < SS - 1; ++s) {
    const float* f0 = ff + (size_t)s * 2 * HW;
    const float* f1 = f0 + HW;
    const unsigned char* on_s = on_all + (size_t)s * HW;

    // ---- Phase A: advect + occupancy marking ----
    if (st >= 0.0f) {
      float xf = floorf(x), yf = floorf(y);
      float wx1 = x - xf, wx0 = 1.0f - wx1;
      float wy1 = y - yf, wy0 = 1.0f - wy1;
      int x0i = clampi((int)xf, 0, WW - 1);
      int x1i = x0i + 1; if (x1i > WW - 1) x1i = WW - 1;
      int y0i = clampi((int)yf, 0, HH - 1);
      int y1i = y0i + 1; if (y1i > HH - 1) y1i = HH - 1;
      float w00 = wy0 * wx0, w01 = wy0 * wx1, w10 = wy1 * wx0, w11 = wy1 * wx1;
      int i00 = y0i * WW + x0i, i01 = y0i * WW + x1i;
      int i10 = y1i * WW + x0i, i11 = y1i * WW + x1i;
      float u = ((f0[i00] * w00 + f0[i01] * w01) + f0[i10] * w10) + f0[i11] * w11;
      float v = ((f1[i00] * w00 + f1[i01] * w01) + f1[i10] * w10) + f1[i11] * w11;
      float xt = x + u, yt = y + v;
      bool marg = (xt > (float)MARGIN) && (yt > (float)MARGIN) &&
                  (xt < (float)(WW - MARGIN)) && (yt < (float)(HH - MARGIN));
      float o00 = (float)on_s[i00], o01 = (float)on_s[i01];
      float o10 = (float)on_s[i10], o11 = (float)on_s[i11];
      float fb = ((o00 * w00 + o01 * w01) + o10 * w10) + o11 * w11;
      bool choose = marg && (fb > 0.5f);
      if (choose) {
        x = xt; y = yt;
        int oy = (int)yt, ox = (int)xt;   // trunc == floor (positive)
        int i0 = ((oy - (MARGIN + 2) + 4099) >> 2) - 1024;  // ceil((oy-12)/4)
        int i1 = ((oy - (MARGIN - 2) + 4096) >> 2) - 1024;  // floor((oy-8)/4)
        int j0 = ((ox - (MARGIN + 2) + 4099) >> 2) - 1024;
        int j1 = ((ox - (MARGIN - 2) + 4096) >> 2) - 1024;
        if (i0 < 0) i0 = 0; if (i1 > GYC - 1) i1 = GYC - 1;
        if (j0 < 0) j0 = 0; if (j1 > GXC - 1) j1 = GXC - 1;
        for (int i = i0; i <= i1; ++i)
          for (int j = j0; j <= j1; ++j)
            occ[i * GXC + j] = (unsigned char)1;   // same-value stores: benign race
      } else {
        st = -1.0f; x = 0.f; y = 0.f;
      }
    }
    grid_barrier(bar, btarget += NBLK);

    // ---- Phase B: ballot counts ----
    unsigned long long cmask = 0ull;
    if (w < CW) {
      int g = w * 64 + lane;
      bool fr = (g < GG) && (occ[g] == 0);
      cmask = __ballot(fr);
      if (lane == 0) wtot_c[w] = __popcll(cmask);
    }
    unsigned long long smask = __ballot(st < 0.0f);
    if (lane == 0) wtot_s[w] = __popcll(smask);
    grid_barrier(bar, btarget += NBLK);

    // ---- Phase C: prefixes over wave totals + stable cand list + occ zero ----
    int pc = 0, tc = 0, ps = 0;
    for (int j = lane; j < NWAVE; j += 64) {
      if (j < CW) { int v = wtot_c[j]; tc += v; if (j < w) pc += v; }
      int v2 = wtot_s[j]; if (j < w) ps += v2;
    }
    for (int o = 32; o > 0; o >>= 1) {
      pc += __shfl_xor(pc, o, 64);
      tc += __shfl_xor(tc, o, 64);
      ps += __shfl_xor(ps, o, 64);
    }
    if ((cmask >> lane) & 1ull) {
      cand[pc + __popcll(cmask & ltmask)] = (unsigned short)(w * 64 + lane);
    }
    if (tid < GG / 4) ((unsigned int*)occ)[tid] = 0u;   // reset for next step
    grid_barrier(bar, btarget += NBLK);

    // ---- Phase D: rank-matched births + write row s+1 ----
    if (st < 0.0f) {
      int r = ps + __popcll(smask & ltmask);
      if (r < tc) {                        // r < min(num_cand, num_free) <=> r < num_cand
        int g = (int)cand[r];
        int ii = g / GXC, jj = g - ii * GXC;
        x = (float)(MARGIN + STEP * jj);
        y = (float)(MARGIN + STEP * ii);
        st = (float)(s + 1);
      }
    }
    X[(size_t)(s + 1) * NSLOT + tid] = x;
    Y[(size_t)(s + 1) * NSLOT + tid] = y;
  }

  Start[tid] = st;
}

// ---------------------------------------------------------------------------
extern "C" void kernel_launch(void* const* d_in, const int* in_sizes, int n_in,
                              void* d_out, int out_size, void* d_ws, size_t ws_size,
                              hipStream_t stream) {
  const float* ff  = (const float*)d_in[0];   // (1,S,2,H,W)
  const float* fbk = (const float*)d_in[1];

  float* X     = (float*)d_out;                       // (S, N)
  float* Y     = X + (size_t)SS * NSLOT;              // (S, N)
  float* Start = Y + (size_t)SS * NSLOT;              // (N,)

  unsigned char*  on_all = (unsigned char*)d_ws;                  // 31*HW B
  unsigned char*  occ    = on_all + (size_t)31 * HW;              // GG B (4-aligned)
  unsigned short* cand   = (unsigned short*)(occ + GG);           // GG ushort
  int*            wtot_c = (int*)((unsigned char*)cand + (size_t)GG * 2);
  int*            wtot_s = wtot_c + CW;
  int*            bar    = wtot_s + NWAVE;

  k_init<<<(GG / 4 + 255) / 256, 256, 0, stream>>>((unsigned int*)occ, bar);

  dim3 gp(HW / 256, 31);
  k_prune<<<gp, 256, 0, stream>>>(ff, fbk, on_all);

  k_steps<<<NBLK, 256, 0, stream>>>(ff, on_all, X, Y, Start,
                                    occ, cand, wtot_c, wtot_s, bar);
}

// Round 4
// 994.191 us; speedup vs baseline: 2.1617x; 2.1617x over previous
//
#include <hip/hip_runtime.h>
#include <cstdint>

// Problem constants (fixed by setup_inputs: H=480, W=1024, S=32, margin=10, step=4)
#define HH 480
#define WW 1024
#define SS 32
#define HW (HH*WW)              // 491520
#define MARGIN 10
#define STEP 4
#define GYC 116                 // len(arange(10, 471, 4))
#define GXC 252                 // len(arange(10, 1015, 4))
#define GG (GYC*GXC)            // 29232 grid candidates
#define NSLOT (2*HH*WW/(STEP*STEP))  // 61440 trajectory slots
#define NBLK (NSLOT/256)        // 240 blocks -> co-resident on 256 CUs
#define NWAVE (NSLOT/64)        // 960 waves
#define CW ((GG+63)/64)         // 457 waves own candidate windows of 64

// Agent-scope (device-coherent, L2-bypass) access helpers. These compile to
// global_load/store with agent-scope cache bits -> served at the coherence
// point, so cross-XCD readers are fresh WITHOUT any buffer_wbl2/buffer_inv
// L2 flush (the R3 killer). Plain cached loads keep using L2 normally.
__device__ __forceinline__ unsigned int aload(const unsigned int* p) {
  return __hip_atomic_load(p, __ATOMIC_RELAXED, __HIP_MEMORY_SCOPE_AGENT);
}
__device__ __forceinline__ void astore(unsigned int* p, unsigned int v) {
  __hip_atomic_store(p, v, __ATOMIC_RELAXED, __HIP_MEMORY_SCOPE_AGENT);
}
__device__ __forceinline__ int aloadi(const int* p) {
  return __hip_atomic_load(p, __ATOMIC_RELAXED, __HIP_MEMORY_SCOPE_AGENT);
}

__device__ __forceinline__ int clampi(int v, int lo, int hi) {
  return v < lo ? lo : (v > hi ? hi : v);
}

// Fence-free grid barrier. Safe because (a) all 240 blocks are co-resident,
// (b) ALL cross-block data uses agent-scope bypass stores, which are globally
// visible once vmcnt drains — and __syncthreads() emits s_waitcnt vmcnt(0)
// before s_barrier, so every wave's bypass stores are visible before thread 0
// publishes the arrival. No cache maintenance ops -> L2 stays warm.
__device__ __forceinline__ void grid_barrier(int* bar, int target) {
  __threadfence_block();     // s_waitcnt only (belt & suspenders)
  __syncthreads();
  if (threadIdx.x == 0) {
    __hip_atomic_fetch_add(bar, 1, __ATOMIC_RELAXED, __HIP_MEMORY_SCOPE_AGENT);
    while (aloadi(bar) < target) __builtin_amdgcn_s_sleep(2);
  }
  __syncthreads();
}

// ---------------------------------------------------------------------------
// K0: zero the occupancy grid (u32/cell) and the barrier counter.
// ---------------------------------------------------------------------------
__global__ __launch_bounds__(256) void k_init(unsigned int* __restrict__ occ,
                                              int* __restrict__ bar)
{
  int idx = blockIdx.x * 256 + threadIdx.x;
  if (idx == 0) *bar = 0;
  if (idx < GG) occ[idx] = 0u;
}

// ---------------------------------------------------------------------------
// K1: batched fwd-bwd consistency prune for all 31 steps (unchanged).
// ---------------------------------------------------------------------------
__global__ __launch_bounds__(256) void k_prune(const float* __restrict__ ff,
                                               const float* __restrict__ fbk,
                                               unsigned char* __restrict__ on)
{
#pragma clang fp contract(off)
  int p = blockIdx.x * 256 + threadIdx.x;
  int s = blockIdx.y;
  int y = p >> 10, x = p & 1023;              // W = 1024
  const float* f0 = ff + (size_t)s * 2 * HW;
  const float* f1 = f0 + HW;
  float fx = f0[p], fy = f1[p];
  float xt = (float)x + fx;
  float yt = (float)y + fy;
  float x0 = floorf(xt), y0 = floorf(yt);
  float wx1 = xt - x0, wx0 = 1.0f - wx1;
  float wy1 = yt - y0, wy0 = 1.0f - wy1;
  int x0i = clampi((int)x0, 0, WW - 1);
  int x1i = x0i + 1; if (x1i > WW - 1) x1i = WW - 1;
  int y0i = clampi((int)y0, 0, HH - 1);
  int y1i = y0i + 1; if (y1i > HH - 1) y1i = HH - 1;
  float w00 = wy0 * wx0, w01 = wy0 * wx1, w10 = wy1 * wx0, w11 = wy1 * wx1;
  int i00 = y0i * WW + x0i, i01 = y0i * WW + x1i;
  int i10 = y1i * WW + x0i, i11 = y1i * WW + x1i;
  const float* b0 = fbk + (size_t)s * 2 * HW;
  const float* b1 = b0 + HW;
  float bw0 = ((b0[i00] * w00 + b0[i01] * w01) + b0[i10] * w10) + b0[i11] * w11;
  float bw1 = ((b1[i00] * w00 + b1[i01] * w01) + b1[i10] * w10) + b1[i11] * w11;
  float t0 = fx + bw0, t1 = fy + bw1;
  float diff = sqrtf(t0 * t0 + t1 * t1);
  float magf = sqrtf(fx * fx + fy * fy);
  float magb = sqrtf(bw0 * bw0 + bw1 * bw1);
  float mag = 0.5f * (magf + magb);
  on[(size_t)s * HW + p] = (diff <= 0.01f * mag + 0.1f) ? (unsigned char)1 : (unsigned char)0;
}

// ---------------------------------------------------------------------------
// K2: persistent scan — all 31 steps in one launch. Thread tid owns slot tid;
// x/y/st live in registers. Per step:
//   A: advect + occ marking (bypass stores)     -> barrier
//   B: ballot counts (occ via bypass loads)     -> barrier
//   C: prefix over wave totals + stable cand list + occ zero -> barrier
//   D: rank-matched births (register-local) + write row s+1
// Stable order = wave asc, lane asc = index asc (matches reference argsort).
// ---------------------------------------------------------------------------
__global__ __launch_bounds__(256, 1) void k_steps(
    const float* __restrict__ ff, const unsigned char* __restrict__ on_all,
    float* __restrict__ X, float* __restrict__ Y, float* __restrict__ Start,
    unsigned int* __restrict__ occ, unsigned int* __restrict__ cand,
    unsigned int* __restrict__ wtot_c, unsigned int* __restrict__ wtot_s, int* bar)
{
#pragma clang fp contract(off)
  const int tid = blockIdx.x * 256 + threadIdx.x;   // slot id
  const int w = tid >> 6;                            // global wave id
  const int lane = tid & 63;
  const unsigned long long ltmask = (1ull << lane) - 1ull;

  float x = 0.f, y = 0.f, st = -1.f;
  if (tid < GG) {
    int ii = tid / GXC, jj = tid - ii * GXC;
    x = (float)(MARGIN + STEP * jj);
    y = (float)(MARGIN + STEP * ii);
    st = 0.f;
  }
  X[tid] = x; Y[tid] = y;   // row 0

  int btarget = 0;

  for (int s = 0; s < SS - 1; ++s) {
    const float* f0 = ff + (size_t)s * 2 * HW;
    const float* f1 = f0 + HW;
    const unsigned char* on_s = on_all + (size_t)s * HW;

    // ---- Phase A: advect + occupancy marking ----
    if (st >= 0.0f) {
      float xf = floorf(x), yf = floorf(y);
      float wx1 = x - xf, wx0 = 1.0f - wx1;
      float wy1 = y - yf, wy0 = 1.0f - wy1;
      int x0i = clampi((int)xf, 0, WW - 1);
      int x1i = x0i + 1; if (x1i > WW - 1) x1i = WW - 1;
      int y0i = clampi((int)yf, 0, HH - 1);
      int y1i = y0i + 1; if (y1i > HH - 1) y1i = HH - 1;
      float w00 = wy0 * wx0, w01 = wy0 * wx1, w10 = wy1 * wx0, w11 = wy1 * wx1;
      int i00 = y0i * WW + x0i, i01 = y0i * WW + x1i;
      int i10 = y1i * WW + x0i, i11 = y1i * WW + x1i;
      float u = ((f0[i00] * w00 + f0[i01] * w01) + f0[i10] * w10) + f0[i11] * w11;
      float v = ((f1[i00] * w00 + f1[i01] * w01) + f1[i10] * w10) + f1[i11] * w11;
      float xt = x + u, yt = y + v;
      bool marg = (xt > (float)MARGIN) && (yt > (float)MARGIN) &&
                  (xt < (float)(WW - MARGIN)) && (yt < (float)(HH - MARGIN));
      float o00 = (float)on_s[i00], o01 = (float)on_s[i01];
      float o10 = (float)on_s[i10], o11 = (float)on_s[i11];
      float fb = ((o00 * w00 + o01 * w01) + o10 * w10) + o11 * w11;
      bool choose = marg && (fb > 0.5f);
      if (choose) {
        x = xt; y = yt;
        int oy = (int)yt, ox = (int)xt;   // trunc == floor (positive)
        int i0 = ((oy - (MARGIN + 2) + 4099) >> 2) - 1024;  // ceil((oy-12)/4)
        int i1 = ((oy - (MARGIN - 2) + 4096) >> 2) - 1024;  // floor((oy-8)/4)
        int j0 = ((ox - (MARGIN + 2) + 4099) >> 2) - 1024;
        int j1 = ((ox - (MARGIN - 2) + 4096) >> 2) - 1024;
        if (i0 < 0) i0 = 0; if (i1 > GYC - 1) i1 = GYC - 1;
        if (j0 < 0) j0 = 0; if (j1 > GXC - 1) j1 = GXC - 1;
        for (int i = i0; i <= i1; ++i)
          for (int j = j0; j <= j1; ++j)
            astore(&occ[i * GXC + j], 1u);   // same-value stores: benign race
      } else {
        st = -1.0f; x = 0.f; y = 0.f;
      }
    }
    grid_barrier(bar, btarget += NBLK);

    // ---- Phase B: ballot counts (coherent occ reads) ----
    unsigned long long cmask = 0ull;
    if (w < CW) {
      int g = w * 64 + lane;
      bool fr = (g < GG) && (aload(&occ[g]) == 0u);
      cmask = __ballot(fr);
      if (lane == 0) astore(&wtot_c[w], (unsigned int)__popcll(cmask));
    }
    unsigned long long smask = __ballot(st < 0.0f);
    if (lane == 0) astore(&wtot_s[w], (unsigned int)__popcll(smask));
    grid_barrier(bar, btarget += NBLK);

    // ---- Phase C: prefixes over wave totals + stable cand list + occ zero ----
    int pc = 0, tc = 0, ps = 0;
    for (int j = lane; j < NWAVE; j += 64) {
      if (j < CW) { int v = (int)aload(&wtot_c[j]); tc += v; if (j < w) pc += v; }
      int v2 = (int)aload(&wtot_s[j]); if (j < w) ps += v2;
    }
    for (int o = 32; o > 0; o >>= 1) {
      pc += __shfl_xor(pc, o, 64);
      tc += __shfl_xor(tc, o, 64);
      ps += __shfl_xor(ps, o, 64);
    }
    if ((cmask >> lane) & 1ull) {
      astore(&cand[pc + __popcll(cmask & ltmask)], (unsigned int)(w * 64 + lane));
    }
    if (tid < GG) astore(&occ[tid], 0u);     // reset for next step
    grid_barrier(bar, btarget += NBLK);

    // ---- Phase D: rank-matched births + write row s+1 ----
    if (st < 0.0f) {
      int r = ps + __popcll(smask & ltmask);
      if (r < tc) {                 // r < min(num_cand, num_free) <=> r < num_cand
        int g = (int)aload(&cand[r]);
        int ii = g / GXC, jj = g - ii * GXC;
        x = (float)(MARGIN + STEP * jj);
        y = (float)(MARGIN + STEP * ii);
        st = (float)(s + 1);
      }
    }
    X[(size_t)(s + 1) * NSLOT + tid] = x;
    Y[(size_t)(s + 1) * NSLOT + tid] = y;
  }

  Start[tid] = st;
}

// ---------------------------------------------------------------------------
extern "C" void kernel_launch(void* const* d_in, const int* in_sizes, int n_in,
                              void* d_out, int out_size, void* d_ws, size_t ws_size,
                              hipStream_t stream) {
  const float* ff  = (const float*)d_in[0];   // (1,S,2,H,W)
  const float* fbk = (const float*)d_in[1];

  float* X     = (float*)d_out;                       // (S, N)
  float* Y     = X + (size_t)SS * NSLOT;              // (S, N)
  float* Start = Y + (size_t)SS * NSLOT;              // (N,)

  unsigned char* on_all = (unsigned char*)d_ws;                   // 31*HW B
  unsigned int*  occ    = (unsigned int*)(on_all + (size_t)31 * HW);  // GG u32
  unsigned int*  cand   = occ + GG;                               // GG u32
  unsigned int*  wtot_c = cand + GG;                              // CW u32
  unsigned int*  wtot_s = wtot_c + CW;                            // NWAVE u32
  int*           bar    = (int*)(wtot_s + NWAVE);

  k_init<<<(GG + 255) / 256, 256, 0, stream>>>(occ, bar);

  dim3 gp(HW / 256, 31);
  k_prune<<<gp, 256, 0, stream>>>(ff, fbk, on_all);

  k_steps<<<NBLK, 256, 0, stream>>>(ff, on_all, X, Y, Start,
                                    occ, cand, wtot_c, wtot_s, bar);
}

// Round 5
// 647.009 us; speedup vs baseline: 3.3216x; 1.5366x over previous
//
#include <hip/hip_runtime.h>
#include <cstdint>

// Problem constants (fixed by setup_inputs: H=480, W=1024, S=32, margin=10, step=4)
#define HH 480
#define WW 1024
#define SS 32
#define HW (HH*WW)              // 491520
#define MARGIN 10
#define STEP 4
#define GYC 116                 // len(arange(10, 471, 4))
#define GXC 252                 // len(arange(10, 1015, 4))
#define GG (GYC*GXC)            // 29232 grid candidates
#define NSLOT (2*HH*WW/(STEP*STEP))  // 61440 trajectory slots
#define NBLK (NSLOT/256)        // 240 blocks -> co-resident on 256 CUs
#define NWAVE (NSLOT/64)        // 960 waves
#define CW ((GG+63)/64)         // 457 candidate bitmap words
#define CWP 512                 // padded word count (per-block scan width)

// Agent-scope (device-coherent, L2-bypass) accessors: fresh across XCDs with
// NO cache-maintenance ops (no buffer_wbl2/buffer_inv -> L2 stays warm).
__device__ __forceinline__ unsigned int aload(const unsigned int* p) {
  return __hip_atomic_load(p, __ATOMIC_RELAXED, __HIP_MEMORY_SCOPE_AGENT);
}
__device__ __forceinline__ void astore(unsigned int* p, unsigned int v) {
  __hip_atomic_store(p, v, __ATOMIC_RELAXED, __HIP_MEMORY_SCOPE_AGENT);
}
__device__ __forceinline__ unsigned long long aload64(const unsigned long long* p) {
  return __hip_atomic_load(p, __ATOMIC_RELAXED, __HIP_MEMORY_SCOPE_AGENT);
}
__device__ __forceinline__ void astore64(unsigned long long* p, unsigned long long v) {
  __hip_atomic_store(p, v, __ATOMIC_RELAXED, __HIP_MEMORY_SCOPE_AGENT);
}

__device__ __forceinline__ int clampi(int v, int lo, int hi) {
  return v < lo ? lo : (v > hi ? hi : v);
}

// Fence-free grid barrier with 8-way striped counters (one per 256B line).
// Safe: all 240 blocks co-resident; all cross-block data uses agent-scope
// bypass ops, globally visible once vmcnt drains — and __syncthreads emits
// s_waitcnt vmcnt(0) before s_barrier, so stores precede the arrival bump.
__device__ __forceinline__ void grid_barrier(int* bar, int target) {
  __syncthreads();
  if (threadIdx.x < 64) {
    if (threadIdx.x == 0)
      __hip_atomic_fetch_add(&bar[(blockIdx.x & 7) << 6], 1,
                             __ATOMIC_RELAXED, __HIP_MEMORY_SCOPE_AGENT);
    const int lane = threadIdx.x;
    for (;;) {
      int v = (lane < 8)
            ? __hip_atomic_load(&bar[lane << 6], __ATOMIC_RELAXED, __HIP_MEMORY_SCOPE_AGENT)
            : 0;
      v += __shfl_xor(v, 1, 64);
      v += __shfl_xor(v, 2, 64);
      v += __shfl_xor(v, 4, 64);     // lanes 0..7 summed within the 8-group
      if (__shfl(v, 0, 64) >= target) break;
      __builtin_amdgcn_s_sleep(1);
    }
  }
  __syncthreads();
}

// ---------------------------------------------------------------------------
// K0: zero occ grid + the 8 barrier stripes (ws is poisoned 0xAA).
// ---------------------------------------------------------------------------
__global__ __launch_bounds__(256) void k_init(unsigned int* __restrict__ occ,
                                              int* __restrict__ bar)
{
  int idx = blockIdx.x * 256 + threadIdx.x;
  if (idx < 512) bar[idx] = 0;
  if (idx < GG) occ[idx] = 0u;
}

// ---------------------------------------------------------------------------
// K1: batched fwd-bwd consistency prune, 2 independent pixels per thread
// (doubles memory-level parallelism; kernel is gather-latency bound).
// ---------------------------------------------------------------------------
__device__ __forceinline__ unsigned char prune_one(const float* __restrict__ f0,
                                                   const float* __restrict__ f1,
                                                   const float* __restrict__ b0,
                                                   const float* __restrict__ b1,
                                                   int p)
{
#pragma clang fp contract(off)
  int y = p >> 10, x = p & 1023;              // W = 1024
  float fx = f0[p], fy = f1[p];
  float xt = (float)x + fx;
  float yt = (float)y + fy;
  float x0 = floorf(xt), y0 = floorf(yt);
  float wx1 = xt - x0, wx0 = 1.0f - wx1;
  float wy1 = yt - y0, wy0 = 1.0f - wy1;
  int x0i = clampi((int)x0, 0, WW - 1);
  int x1i = x0i + 1; if (x1i > WW - 1) x1i = WW - 1;
  int y0i = clampi((int)y0, 0, HH - 1);
  int y1i = y0i + 1; if (y1i > HH - 1) y1i = HH - 1;
  float w00 = wy0 * wx0, w01 = wy0 * wx1, w10 = wy1 * wx0, w11 = wy1 * wx1;
  int i00 = y0i * WW + x0i, i01 = y0i * WW + x1i;
  int i10 = y1i * WW + x0i, i11 = y1i * WW + x1i;
  float bw0 = ((b0[i00] * w00 + b0[i01] * w01) + b0[i10] * w10) + b0[i11] * w11;
  float bw1 = ((b1[i00] * w00 + b1[i01] * w01) + b1[i10] * w10) + b1[i11] * w11;
  float t0 = fx + bw0, t1 = fy + bw1;
  float diff = sqrtf(t0 * t0 + t1 * t1);
  float magf = sqrtf(fx * fx + fy * fy);
  float magb = sqrtf(bw0 * bw0 + bw1 * bw1);
  float mag = 0.5f * (magf + magb);
  return (diff <= 0.01f * mag + 0.1f) ? (unsigned char)1 : (unsigned char)0;
}

__global__ __launch_bounds__(256) void k_prune(const float* __restrict__ ff,
                                               const float* __restrict__ fbk,
                                               unsigned char* __restrict__ on)
{
  int p = blockIdx.x * 256 + threadIdx.x;     // first pixel; second is p + HW/2
  int s = blockIdx.y;
  const float* f0 = ff + (size_t)s * 2 * HW;
  const float* f1 = f0 + HW;
  const float* b0 = fbk + (size_t)s * 2 * HW;
  const float* b1 = b0 + HW;
  unsigned char r0 = prune_one(f0, f1, b0, b1, p);
  unsigned char r1 = prune_one(f0, f1, b0, b1, p + HW / 2);
  on[(size_t)s * HW + p] = r0;
  on[(size_t)s * HW + p + HW / 2] = r1;
}

// ---------------------------------------------------------------------------
// K2: persistent scan — all 31 steps, TWO grid barriers per step.
//   A: advect + occ marks (u32 bypass stores); publish per-wave slot-free
//      counts (parity-buffered)                              -> barrier
//   B: candidate waves ballot occ -> u64 bitmap word (bypass store),
//      self-zero occ for next step                           -> barrier
//   CD: every block loads the 457-word bitmap into LDS, builds the popcount
//      prefix locally (shuffle scan), births = LDS binary search by rank.
// Stable order = word asc, bit asc = index asc (matches reference argsort).
// ---------------------------------------------------------------------------
__global__ __launch_bounds__(256, 1) void k_steps(
    const float* __restrict__ ff, const unsigned char* __restrict__ on_all,
    float* __restrict__ X, float* __restrict__ Y, float* __restrict__ Start,
    unsigned int* __restrict__ occ, unsigned long long* __restrict__ bitmap,
    unsigned int* __restrict__ wtot_s, int* bar)
{
#pragma clang fp contract(off)
  const int tid = blockIdx.x * 256 + threadIdx.x;   // slot id
  const int w = tid >> 6;                            // global wave id
  const int lane = tid & 63;
  const int wv = threadIdx.x >> 6;                   // wave-in-block 0..3
  const unsigned long long ltmask = (1ull << lane) - 1ull;

  __shared__ unsigned long long wds[CWP];   // bitmap copy (4 KB)
  __shared__ unsigned int pref[CWP];        // inclusive popcount prefix (2 KB)
  __shared__ int wsum[4];

  float x = 0.f, y = 0.f, st = -1.f;
  if (tid < GG) {
    int ii = tid / GXC, jj = tid - ii * GXC;
    x = (float)(MARGIN + STEP * jj);
    y = (float)(MARGIN + STEP * ii);
    st = 0.f;
  }
  X[tid] = x; Y[tid] = y;   // row 0

  int btarget = 0;

  for (int s = 0; s < SS - 1; ++s) {
    const float* f0 = ff + (size_t)s * 2 * HW;
    const float* f1 = f0 + HW;
    const unsigned char* on_s = on_all + (size_t)s * HW;

    // ---- Phase A: advect + occupancy marking + publish slot-free count ----
    if (st >= 0.0f) {
      float xf = floorf(x), yf = floorf(y);
      float wx1 = x - xf, wx0 = 1.0f - wx1;
      float wy1 = y - yf, wy0 = 1.0f - wy1;
      int x0i = clampi((int)xf, 0, WW - 1);
      int x1i = x0i + 1; if (x1i > WW - 1) x1i = WW - 1;
      int y0i = clampi((int)yf, 0, HH - 1);
      int y1i = y0i + 1; if (y1i > HH - 1) y1i = HH - 1;
      float w00 = wy0 * wx0, w01 = wy0 * wx1, w10 = wy1 * wx0, w11 = wy1 * wx1;
      int i00 = y0i * WW + x0i, i01 = y0i * WW + x1i;
      int i10 = y1i * WW + x0i, i11 = y1i * WW + x1i;
      float u = ((f0[i00] * w00 + f0[i01] * w01) + f0[i10] * w10) + f0[i11] * w11;
      float v = ((f1[i00] * w00 + f1[i01] * w01) + f1[i10] * w10) + f1[i11] * w11;
      float xt = x + u, yt = y + v;
      bool marg = (xt > (float)MARGIN) && (yt > (float)MARGIN) &&
                  (xt < (float)(WW - MARGIN)) && (yt < (float)(HH - MARGIN));
      float o00 = (float)on_s[i00], o01 = (float)on_s[i01];
      float o10 = (float)on_s[i10], o11 = (float)on_s[i11];
      float fb = ((o00 * w00 + o01 * w01) + o10 * w10) + o11 * w11;
      bool choose = marg && (fb > 0.5f);
      if (choose) {
        x = xt; y = yt;
        int oy = (int)yt, ox = (int)xt;   // trunc == floor (positive)
        int i0 = ((oy - (MARGIN + 2) + 4099) >> 2) - 1024;  // ceil((oy-12)/4)
        int i1 = ((oy - (MARGIN - 2) + 4096) >> 2) - 1024;  // floor((oy-8)/4)
        int j0 = ((ox - (MARGIN + 2) + 4099) >> 2) - 1024;
        int j1 = ((ox - (MARGIN - 2) + 4096) >> 2) - 1024;
        if (i0 < 0) i0 = 0; if (i1 > GYC - 1) i1 = GYC - 1;
        if (j0 < 0) j0 = 0; if (j1 > GXC - 1) j1 = GXC - 1;
        for (int i = i0; i <= i1; ++i)
          for (int j = j0; j <= j1; ++j)
            astore(&occ[i * GXC + j], 1u);   // same-value stores: benign race
      } else {
        st = -1.0f; x = 0.f; y = 0.f;
      }
    }
    unsigned long long smask = __ballot(st < 0.0f);
    if (lane == 0)
      astore(&wtot_s[(s & 1) * NWAVE + w], (unsigned int)__popcll(smask));
    grid_barrier(bar, btarget += NBLK);

    // ---- Phase B: compress occ -> bitmap, self-zero occ ----
    if (w < CW) {
      int g = w * 64 + lane;
      bool fr = (g < GG) && (aload(&occ[g]) == 0u);
      unsigned long long cm = __ballot(fr);
      if (lane == 0) astore64(&bitmap[w], cm);
      if (g < GG) astore(&occ[g], 0u);       // reset for next step's marks
    }
    grid_barrier(bar, btarget += NBLK);

    // ---- Phase CD: block-local prefix over the bitmap + births ----
    {
      int t = threadIdx.x;
      int e0 = 2 * t, e1 = 2 * t + 1;
      unsigned long long m0 = (e0 < CW) ? aload64(&bitmap[e0]) : 0ull;
      unsigned long long m1 = (e1 < CW) ? aload64(&bitmap[e1]) : 0ull;
      wds[e0] = m0; wds[e1] = m1;
      int p0 = __popcll(m0), p1 = __popcll(m1);
      int v = p0 + p1;
      for (int o = 1; o < 64; o <<= 1) {
        int uu = __shfl_up(v, o, 64);
        if (lane >= o) v += uu;
      }
      if (lane == 63) wsum[wv] = v;
      __syncthreads();
      int base = 0;
      for (int j2 = 0; j2 < wv; ++j2) base += wsum[j2];
      pref[e0] = (unsigned int)(base + v - p1);
      pref[e1] = (unsigned int)(base + v);
      __syncthreads();
    }
    int tc = (int)pref[CWP - 1];              // total free candidates

    // slot-rank prefix: sum of wtot_s over waves < w (parity buffer)
    int ps;
    {
      const unsigned int* ws = wtot_s + (s & 1) * NWAVE;
      int acc = 0;
      for (int j = lane; j < NWAVE; j += 64) {
        unsigned int v2 = aload(&ws[j]);
        if (j < w) acc += (int)v2;
      }
      for (int o = 32; o > 0; o >>= 1) acc += __shfl_xor(acc, o, 64);
      ps = acc;
    }

    if (st < 0.0f) {
      int r = ps + __popcll(smask & ltmask);
      if (r < tc) {                  // r < min(num_cand, num_free) <=> r < num_cand
        // word k containing rank r: largest k with pref[k-1] <= r
        int k = 0;
        for (int b = 256; b >= 1; b >>= 1) {
          int nk = k + b;
          if (nk <= CWP - 1 && (int)pref[nk - 1] <= r) k = nk;
        }
        int j = r - (k ? (int)pref[k - 1] : 0);
        unsigned long long m = wds[k];
        int lo = 0;                  // position of the (j+1)-th set bit
        for (int b = 32; b >= 1; b >>= 1) {
          int nb = lo + b;
          unsigned long long mask = (nb >= 64) ? ~0ull : ((1ull << nb) - 1ull);
          if (__popcll(m & mask) <= j) lo = nb;
        }
        int g = k * 64 + lo;
        int ii = g / GXC, jj = g - ii * GXC;
        x = (float)(MARGIN + STEP * jj);
        y = (float)(MARGIN + STEP * ii);
        st = (float)(s + 1);
      }
    }
    X[(size_t)(s + 1) * NSLOT + tid] = x;
    Y[(size_t)(s + 1) * NSLOT + tid] = y;
  }

  Start[tid] = st;
}

// ---------------------------------------------------------------------------
extern "C" void kernel_launch(void* const* d_in, const int* in_sizes, int n_in,
                              void* d_out, int out_size, void* d_ws, size_t ws_size,
                              hipStream_t stream) {
  const float* ff  = (const float*)d_in[0];   // (1,S,2,H,W)
  const float* fbk = (const float*)d_in[1];

  float* X     = (float*)d_out;                       // (S, N)
  float* Y     = X + (size_t)SS * NSLOT;              // (S, N)
  float* Start = Y + (size_t)SS * NSLOT;              // (N,)

  unsigned char*      on_all = (unsigned char*)d_ws;                      // 31*HW B
  unsigned int*       occ    = (unsigned int*)(on_all + (size_t)31 * HW); // GG u32
  unsigned long long* bitmap = (unsigned long long*)(occ + GG);           // CW u64
  unsigned int*       wtot_s = (unsigned int*)(bitmap + CW);              // 2*NWAVE u32
  int*                bar    = (int*)(wtot_s + 2 * NWAVE);                // 512 ints

  k_init<<<(GG + 255) / 256, 256, 0, stream>>>(occ, bar);

  dim3 gp(HW / 512, 31);
  k_prune<<<gp, 256, 0, stream>>>(ff, fbk, on_all);

  k_steps<<<NBLK, 256, 0, stream>>>(ff, on_all, X, Y, Start,
                                    occ, bitmap, wtot_s, bar);
}